// Round 8
// baseline (487.796 us; speedup 1.0000x reference)
//
#include <hip/hip_runtime.h>
#include <hip/hip_bf16.h>

#define N_TOK 4096
#define DIM   1024
#define HID   4096
#define NEXP  8
#define NPOS  8192

#define BKS   64                       // K-tile (shorts)
#define MAXT  72                       // BM=128 m-tiles max
#define G1    (MAXT * (HID/128))       // 2304 ffn1 blocks
#define G2    (MAXT * (DIM/128) * 2)   // 1152 ffn2 blocks (split-K=2)
#define T1J   8192                     // W1 transpose 64x64 tiles
#define T2J   8192                     // W2 transpose 64x64 tiles
#define BUFB  16384                    // bytes per LDS buffer (128 rows x 128 B)

typedef float  f32x4  __attribute__((ext_vector_type(4)));
typedef __bf16 bf16x8 __attribute__((ext_vector_type(8)));
typedef unsigned short us8 __attribute__((ext_vector_type(8)));

__device__ __forceinline__ unsigned short f2bf(float f) {
  __hip_bfloat16 h = __float2bfloat16(f);
  return *reinterpret_cast<unsigned short*>(&h);
}
__device__ __forceinline__ void gload16(const void* g, void* l) {
  __builtin_amdgcn_global_load_lds(
      (const __attribute__((address_space(1))) unsigned int*)g,
      (__attribute__((address_space(3))) unsigned int*)l, 16, 0, 0);
}
#define BAR()    __builtin_amdgcn_s_barrier()
#define WAITV(n) asm volatile("s_waitcnt vmcnt(" #n ")" ::: "memory")
#define WAITL()  asm volatile("s_waitcnt lgkmcnt(0)" ::: "memory")

// ===== 2-phase counted-vmcnt grouped-GEMM core: BM=BN=128, BK=64, 256 thr =====
// LDS per tile: [128 rows][128 B]; 16B-slot s of row r stored at s^(r&7)
// (staged via inverse-swizzled GLOBAL source, linear LDS dest; read with XOR).
// Per K-step: 8 gloads staged for t+1, WAITV(8) -> tile t landed, 16 ds_read_b128,
// 32 MFMA, WAITL+BAR. 2 blocks/CU at 64 KiB LDS.
template<int NKT>
__device__ __forceinline__ void gemm_core(
    const unsigned short* (&ap)[4], const unsigned short* (&bp)[4],
    char* __restrict__ As, char* __restrict__ Bs, f32x4 (&acc)[4][4])
{
  const int tid = threadIdx.x;
  const int w = tid >> 6, l = tid & 63;
  const int wr = w >> 1, wc = w & 1;          // 2x2 wave grid, 64x64 out each
  const int fr = l & 15, q = l >> 4;

  auto STAGE = [&](int t, int buf) {
    const int kt = t * BKS;
    char* Ad = As + buf * BUFB + tid * 16;
    char* Bd = Bs + buf * BUFB + tid * 16;
#pragma unroll
    for (int g = 0; g < 4; g++) {
      gload16(ap[g] + kt, Ad + g * 4096);
      gload16(bp[g] + kt, Bd + g * 4096);
    }
  };

  STAGE(0, 0);
  int cur = 0;
#pragma unroll 1
  for (int t = 0; t < NKT; ++t) {
    if (t + 1 < NKT) { STAGE(t + 1, cur ^ 1); WAITV(8); }
    else             { WAITV(0); }
    BAR();                                     // tile t ready for all waves
    const char* Ab = As + cur * BUFB;
    const char* Bb = Bs + cur * BUFB;
    bf16x8 af[2][4], bf[2][4];
#pragma unroll
    for (int kk = 0; kk < 2; kk++) {
#pragma unroll
      for (int m = 0; m < 4; m++) {
        const int row = wr * 64 + m * 16 + fr;
        const int slot = (kk * 4 + q) ^ (row & 7);
        af[kk][m] = *reinterpret_cast<const bf16x8*>(Ab + row * 128 + slot * 16);
      }
#pragma unroll
      for (int n = 0; n < 4; n++) {
        const int row = wc * 64 + n * 16 + fr;
        const int slot = (kk * 4 + q) ^ (row & 7);
        bf[kk][n] = *reinterpret_cast<const bf16x8*>(Bb + row * 128 + slot * 16);
      }
    }
#pragma unroll
    for (int kk = 0; kk < 2; kk++)
#pragma unroll
      for (int m = 0; m < 4; m++)
#pragma unroll
        for (int n = 0; n < 4; n++)
          acc[m][n] = __builtin_amdgcn_mfma_f32_16x16x32_bf16(af[kk][m], bf[kk][n],
                                                              acc[m][n], 0, 0, 0);
    WAITL(); BAR();                            // all waves done reading buf cur
    cur ^= 1;
  }
}

// ============ K1: gate (+x->bf16) fused with W1 transpose ============
__global__ __launch_bounds__(256) void gate_t1_kernel(
    const float* __restrict__ x, const float* __restrict__ Wg,
    const float* __restrict__ bg, int* __restrict__ topk_idx,
    float* __restrict__ topk_w, int* __restrict__ expert_count,
    unsigned short* __restrict__ xb,
    const float* __restrict__ W1, unsigned short* __restrict__ Wt1)
{
  __shared__ float S[64][67];
  const int tid = threadIdx.x;
  const int bx = blockIdx.x;

  if (bx >= N_TOK/4) {               // ---- W1 transpose: [1024][4096] -> [4096][1024]
    const int tj = bx - N_TOK/4;
    const int e  = tj >> 10;
    const int rem = tj & 1023;
    const int r0 = (rem >> 6) * 64;  // over DIM
    const int c0 = (rem & 63) * 64;  // over HID
    const float* s = W1 + (size_t)e * DIM * HID;
    unsigned short* d = Wt1 + (size_t)e * DIM * HID;
    {
      const int rr = tid >> 2, cc = (tid & 3) * 16;
      const float* sp = s + (size_t)(r0 + rr) * HID + c0 + cc;
#pragma unroll
      for (int j = 0; j < 4; j++) {
        f32x4 v = *reinterpret_cast<const f32x4*>(sp + j * 4);
        S[rr][cc + j*4 + 0] = v.x;
        S[rr][cc + j*4 + 1] = v.y;
        S[rr][cc + j*4 + 2] = v.z;
        S[rr][cc + j*4 + 3] = v.w;
      }
    }
    __syncthreads();
    {
      const int hh = tid >> 2, dbase = (tid & 3) * 16;
      us8 o0, o1;
#pragma unroll
      for (int i = 0; i < 8; i++) o0[i] = f2bf(S[dbase + i][hh]);
#pragma unroll
      for (int i = 0; i < 8; i++) o1[i] = f2bf(S[dbase + 8 + i][hh]);
      unsigned short* dp = d + (size_t)(c0 + hh) * DIM + r0 + dbase;
      *reinterpret_cast<us8*>(dp)     = o0;
      *reinterpret_cast<us8*>(dp + 8) = o1;
    }
    return;
  }

  // ---- gate role ----
  const int wave = tid >> 6, lane = tid & 63;
  const int t = bx * 4 + wave;
  const float* xr = x + (size_t)t * DIM;
  unsigned short* xbr = xb + (size_t)t * DIM;

  float acc[NEXP];
#pragma unroll
  for (int e = 0; e < NEXP; e++) acc[e] = 0.f;
  for (int d = lane; d < DIM; d += 64) {
    float xv = xr[d];
    xbr[d] = f2bf(xv);
    const f32x4* wr = reinterpret_cast<const f32x4*>(Wg + (size_t)d * NEXP);
    f32x4 w0 = wr[0], w1 = wr[1];
    acc[0] += xv * w0.x; acc[1] += xv * w0.y; acc[2] += xv * w0.z; acc[3] += xv * w0.w;
    acc[4] += xv * w1.x; acc[5] += xv * w1.y; acc[6] += xv * w1.z; acc[7] += xv * w1.w;
  }
#pragma unroll
  for (int e = 0; e < NEXP; e++) {
#pragma unroll
    for (int off = 32; off > 0; off >>= 1)
      acc[e] += __shfl_xor(acc[e], off, 64);
  }
  if (lane == 0) {
    float s[NEXP];
#pragma unroll
    for (int e = 0; e < NEXP; e++) s[e] = acc[e] + bg[e];
    int i0 = 0; float b0 = s[0];
#pragma unroll
    for (int e = 1; e < NEXP; e++) if (s[e] > b0) { b0 = s[e]; i0 = e; }
    int i1 = -1; float b1v = -3.4e38f;
#pragma unroll
    for (int e = 0; e < NEXP; e++) if (e != i0 && s[e] > b1v) { b1v = s[e]; i1 = e; }
    float e1 = __expf(b1v - b0);
    float inv = 1.f / (1.f + e1);
    topk_idx[t*2]   = i0;  topk_idx[t*2+1] = i1;
    topk_w[t*2]     = inv; topk_w[t*2+1]   = e1 * inv;
    atomicAdd(&expert_count[i0], 1);
    atomicAdd(&expert_count[i1], 1);
  }
}

// ---------------- routing: scan + BM=128 tile table + deterministic scatter --------
__global__ void route_kernel(const int* __restrict__ expert_count,
                             int* __restrict__ expert_offset,
                             int* __restrict__ table, int* __restrict__ nt,
                             const int* __restrict__ topk_idx,
                             const float* __restrict__ topk_w,
                             int* __restrict__ pair_token, float* __restrict__ pair_w)
{
  __shared__ int soff[NEXP];
  if (threadIdx.x == 0) {
    int off = 0, a = 0;
    for (int e = 0; e < NEXP; e++) {
      expert_offset[e] = off; soff[e] = off;
      int c = expert_count[e];
      for (int r = 0; r < c; r += 128) {
        table[a*4+0] = e; table[a*4+1] = off + r;
        table[a*4+2] = (c - r) < 128 ? (c - r) : 128; a++;
      }
      off += c;
    }
    expert_offset[NEXP] = off;
    *nt = a;
  }
  __syncthreads();
  const int e = threadIdx.x >> 6;
  const int lane = threadIdx.x & 63;
  int base = soff[e];
  for (int a0 = 0; a0 < NPOS; a0 += 64) {
    int a = a0 + lane;
    int idx = topk_idx[a];
    bool f = (idx == e);
    unsigned long long m = __ballot(f);
    if (f) {
      int pos = base + __popcll(m & ((1ull << lane) - 1ull));
      pair_token[pos] = a >> 1;
      pair_w[pos]     = topk_w[a];
    }
    base += __popcll(m);
  }
}

// ---------------- standalone transpose (fallback path only) ----------------
__global__ __launch_bounds__(256) void transpose_kernel(const float* __restrict__ src,
                                                        unsigned short* __restrict__ dst,
                                                        int R, int C)
{
  __shared__ float S[64][67];
  const int e = blockIdx.z;
  const float* s = src + (size_t)e * R * C;
  unsigned short* d = dst + (size_t)e * R * C;
  const int r0 = blockIdx.y * 64, c0 = blockIdx.x * 64;
  const int tid = threadIdx.x;
  {
    const int rr = tid >> 2, cc = (tid & 3) * 16;
    const float* sp = s + (size_t)(r0 + rr) * C + c0 + cc;
#pragma unroll
    for (int j = 0; j < 4; j++) {
      f32x4 v = *reinterpret_cast<const f32x4*>(sp + j * 4);
      S[rr][cc + j*4 + 0] = v.x;
      S[rr][cc + j*4 + 1] = v.y;
      S[rr][cc + j*4 + 2] = v.z;
      S[rr][cc + j*4 + 3] = v.w;
    }
  }
  __syncthreads();
  {
    const int hh = tid >> 2, dbase = (tid & 3) * 16;
    us8 o0, o1;
#pragma unroll
    for (int i = 0; i < 8; i++) o0[i] = f2bf(S[dbase + i][hh]);
#pragma unroll
    for (int i = 0; i < 8; i++) o1[i] = f2bf(S[dbase + 8 + i][hh]);
    unsigned short* dp = d + (size_t)(c0 + hh) * R + r0 + dbase;
    *reinterpret_cast<us8*>(dp)     = o0;
    *reinterpret_cast<us8*>(dp + 8) = o1;
  }
}

// ============ K3: FFN1 (BM=128 BN=128 BK=64, 256 thr) + fused W2 transpose ============
__global__ __launch_bounds__(256) void ffn1_t2_kernel(
    const unsigned short* __restrict__ xb, const unsigned short* __restrict__ Wt1,
    const float* __restrict__ b1, const int* __restrict__ pair_token,
    const int* __restrict__ table, const int* __restrict__ nt,
    unsigned short* __restrict__ h_buf,
    const float* __restrict__ W2, unsigned short* __restrict__ Wt2, int t2jobs)
{
  __shared__ __align__(16) char smem[66048];   // A 32K | B 32K | tok 512
  const int tid = threadIdx.x;
  const int bx = blockIdx.x;

  if (bx >= G1) {                    // ---- W2 transpose: [4096][1024] -> [1024][4096]
    const int tj = bx - G1;
    if (tj >= t2jobs) return;
    float (*S)[67] = (float(*)[67])smem;
    const int e   = tj >> 10;
    const int rem = tj & 1023;
    const int r0 = (rem >> 4) * 64;  // over HID (64 tiles)
    const int c0 = (rem & 15) * 64;  // over DIM (16 tiles)
    const float* s = W2 + (size_t)e * HID * DIM;
    unsigned short* d = Wt2 + (size_t)e * HID * DIM;
    {
      const int rr = tid >> 2, cc = (tid & 3) * 16;
      const float* sp = s + (size_t)(r0 + rr) * DIM + c0 + cc;
#pragma unroll
      for (int j = 0; j < 4; j++) {
        f32x4 v = *reinterpret_cast<const f32x4*>(sp + j * 4);
        S[rr][cc + j*4 + 0] = v.x;
        S[rr][cc + j*4 + 1] = v.y;
        S[rr][cc + j*4 + 2] = v.z;
        S[rr][cc + j*4 + 3] = v.w;
      }
    }
    __syncthreads();
    {
      const int hh = tid >> 2, dbase = (tid & 3) * 16;
      us8 o0, o1;
#pragma unroll
      for (int i = 0; i < 8; i++) o0[i] = f2bf(S[dbase + i][hh]);
#pragma unroll
      for (int i = 0; i < 8; i++) o1[i] = f2bf(S[dbase + 8 + i][hh]);
      unsigned short* dp = d + (size_t)(c0 + hh) * HID + r0 + dbase;
      *reinterpret_cast<us8*>(dp)     = o0;
      *reinterpret_cast<us8*>(dp + 8) = o1;
    }
    return;
  }

  // ---- ffn1 role ----
  int wg = bx;                       // 2304 % 8 == 0, bijective XCD swizzle
  wg = (wg & 7) * (G1/8) + (wg >> 3);
  const int mt = wg % MAXT;
  const int n0 = (wg / MAXT) * 128;
  if (mt >= *nt) return;
  const int e = table[mt*4+0], row_start = table[mt*4+1], rows_valid = table[mt*4+2];

  char* As = smem;
  char* Bs = smem + 2 * BUFB;
  int* tok = (int*)(smem + 4 * BUFB);

  if (tid < 128) tok[tid] = pair_token[row_start + (tid < rows_valid ? tid : 0)];
  __syncthreads();

  const int sr = tid >> 3;                        // stage row 0..31 (+g*32)
  const int soff = 8 * ((tid & 7) ^ (sr & 7));    // inverse swizzle on source
  const unsigned short* We = Wt1 + (size_t)e * HID * DIM;
  const unsigned short* ap[4];
  const unsigned short* bp[4];
#pragma unroll
  for (int g = 0; g < 4; g++) {
    ap[g] = xb + (size_t)tok[g*32 + sr] * DIM + soff;
    bp[g] = We + (size_t)(n0 + g*32 + sr) * DIM + soff;
  }

  f32x4 acc[4][4];
#pragma unroll
  for (int m = 0; m < 4; m++)
#pragma unroll
    for (int n = 0; n < 4; n++) acc[m][n] = (f32x4){0.f, 0.f, 0.f, 0.f};

  gemm_core<DIM/BKS>(ap, bp, As, Bs, acc);

  const int w = tid >> 6, l = tid & 63;
  const int wr = w >> 1, wc = w & 1;
  const int crow = (l >> 4) * 4, ccol = l & 15;
#pragma unroll
  for (int n = 0; n < 4; n++) {
    const int cg = n0 + wc*64 + n*16 + ccol;
    const float bias = b1[(size_t)e * HID + cg];
#pragma unroll
    for (int m = 0; m < 4; m++) {
#pragma unroll
      for (int j = 0; j < 4; j++) {
        int r = wr*64 + m*16 + crow + j;
        if (r < rows_valid)
          h_buf[(size_t)(row_start + r) * HID + cg] = f2bf(fmaxf(acc[m][n][j] + bias, 0.f));
      }
    }
  }
}

// ============ K4: FFN2 (BM=128 BN=128 BK=64, 256 thr), split-K=2, atomic combine ======
__global__ __launch_bounds__(256) void ffn2_kernel(
    const unsigned short* __restrict__ h_buf, const unsigned short* __restrict__ Wt2,
    const float* __restrict__ b2, const int* __restrict__ pair_token,
    const float* __restrict__ pair_w, const int* __restrict__ table,
    const int* __restrict__ nt, float* __restrict__ out)
{
  __shared__ __align__(16) char smem[4 * BUFB];

  int wg = blockIdx.x;                       // 1152 % 8 == 0
  wg = (wg & 7) * (G2/8) + (wg >> 3);
  const int kh  = wg / (MAXT * 8);           // 0..1
  const int rem = wg % (MAXT * 8);
  const int mt  = rem % MAXT;
  const int n0  = (rem / MAXT) * 128;
  if (mt >= *nt) return;
  const int e = table[mt*4+0], row_start = table[mt*4+1], rows_valid = table[mt*4+2];

  const int tid = threadIdx.x;
  const int sr = tid >> 3;
  const int soff = 8 * ((tid & 7) ^ (sr & 7));
  const int kofs = kh * (HID / 2);

  char* As = smem;
  char* Bs = smem + 2 * BUFB;

  const unsigned short* We = Wt2 + (size_t)e * DIM * HID;
  const unsigned short* ap[4];
  const unsigned short* bp[4];
#pragma unroll
  for (int g = 0; g < 4; g++) {
    int r = row_start + g*32 + sr; if (r > NPOS - 1) r = NPOS - 1;
    ap[g] = h_buf + (size_t)r * HID + kofs + soff;
    bp[g] = We + (size_t)(n0 + g*32 + sr) * HID + kofs + soff;
  }

  f32x4 acc[4][4];
#pragma unroll
  for (int m = 0; m < 4; m++)
#pragma unroll
    for (int n = 0; n < 4; n++) acc[m][n] = (f32x4){0.f, 0.f, 0.f, 0.f};

  gemm_core<(HID/2)/BKS>(ap, bp, As, Bs, acc);

  const int w = tid >> 6, l = tid & 63;
  const int wr = w >> 1, wc = w & 1;
  const int crow = (l >> 4) * 4, ccol = l & 15;
  float bias[4];
#pragma unroll
  for (int n = 0; n < 4; n++)
    bias[n] = (kh == 0) ? b2[(size_t)e * DIM + n0 + wc*64 + n*16 + ccol] : 0.f;

#pragma unroll
  for (int m = 0; m < 4; m++) {
#pragma unroll
    for (int j = 0; j < 4; j++) {
      int r = wr*64 + m*16 + crow + j;
      if (r < rows_valid) {
        int pos = row_start + r;
        int t   = pair_token[pos];
        float wv = pair_w[pos];
        float* orow = out + (size_t)t * DIM;
#pragma unroll
        for (int n = 0; n < 4; n++)
          atomicAdd(&orow[n0 + wc*64 + n*16 + ccol], (acc[m][n][j] + bias[n]) * wv);
      }
    }
  }
}

extern "C" void kernel_launch(void* const* d_in, const int* in_sizes, int n_in,
                              void* d_out, int out_size, void* d_ws, size_t ws_size,
                              hipStream_t stream) {
  const float* x  = (const float*)d_in[0];
  const float* Wg = (const float*)d_in[1];
  const float* bg = (const float*)d_in[2];
  const float* W1 = (const float*)d_in[3];
  const float* b1 = (const float*)d_in[4];
  const float* W2 = (const float*)d_in[5];
  const float* b2 = (const float*)d_in[6];
  float* out = (float*)d_out;

  char* ws = (char*)d_ws;
  const size_t MB = 1024 * 1024;
  int*   expert_count  = (int*)(ws + 0);
  int*   nt            = (int*)(ws + 64);
  int*   expert_offset = (int*)(ws + 128);
  int*   table         = (int*)(ws + 1024);
  int*   topk_idx      = (int*)(ws + 4096);
  float* topk_w        = (float*)(ws + 4096 + 32768);
  int*   pair_token    = (int*)(ws + 4096 + 65536);
  float* pair_w        = (float*)(ws + 4096 + 98304);
  unsigned short* xb   = (unsigned short*)(ws + 1*MB);    //  8 MiB
  unsigned short* Wt1  = (unsigned short*)(ws + 9*MB);    // 64 MiB

  const bool roomy = ws_size >= 201ull * MB;
  unsigned short* Wt2 = roomy ? (unsigned short*)(ws + 73*MB) : Wt1;
  unsigned short* h   = roomy ? (unsigned short*)(ws + 137*MB)
                              : (unsigned short*)(ws + 73*MB);

  hipMemsetAsync(ws, 0, 256, stream);
  hipMemsetAsync(d_out, 0, (size_t)N_TOK * DIM * sizeof(float), stream);

  gate_t1_kernel<<<N_TOK/4 + T1J, 256, 0, stream>>>(x, Wg, bg, topk_idx, topk_w,
                                                    expert_count, xb, W1, Wt1);
  route_kernel<<<1, 512, 0, stream>>>(expert_count, expert_offset, table, nt,
                                      topk_idx, topk_w, pair_token, pair_w);
  if (roomy) {
    ffn1_t2_kernel<<<G1 + T2J, 256, 0, stream>>>(xb, Wt1, b1, pair_token, table,
                                                 nt, h, W2, Wt2, T2J);
  } else {
    ffn1_t2_kernel<<<G1, 256, 0, stream>>>(xb, Wt1, b1, pair_token, table,
                                           nt, h, W2, Wt2, 0);
    transpose_kernel<<<dim3(DIM/64, HID/64, NEXP), 256, 0, stream>>>(W2, Wt2, HID, DIM);
  }
  ffn2_kernel<<<G2, 256, 0, stream>>>(h, Wt2, b2, pair_token, pair_w, table, nt, out);
}